// Round 13
// baseline (330.276 us; speedup 1.0000x reference)
//
#include <hip/hip_runtime.h>
#include <hip/hip_bf16.h>
#include <math.h>

#define BD 2
#define HD 16
#define NSEQ 8192
#define DDIM 64
#define NPROJ 7
#define KBLK 256
#define NSAMP 256
#define NBH (BD*HD)           // 32
#define NB (NSEQ/KBLK)        // 32

typedef short bf16x8 __attribute__((ext_vector_type(8)));
typedef short bf16x4 __attribute__((ext_vector_type(4)));
typedef float f32x4 __attribute__((ext_vector_type(4)));

// pack two f32 -> u32 of 2 bf16 (RTNE via v_cvt_pk_bf16_f32)
__device__ __forceinline__ unsigned int pk2bf(float a, float b) {
    union { __hip_bfloat162 h; unsigned int u; } t;
    t.h = __float22bfloat162_rn(make_float2(a, b));
    return t.u;
}

// async global->LDS, 16B/lane: LDS dest = wave-uniform base + lane*16,
// global src is PER-LANE (the gather happens here, zero VGPR staging cost)
__device__ __forceinline__ void gload16(const void* gsrc, void* lds) {
    __builtin_amdgcn_global_load_lds(
        (const __attribute__((address_space(1))) unsigned int*)gsrc,
        (__attribute__((address_space(3))) unsigned int*)lds, 16, 0, 0);
}

// ---------------------------------------------------------------------------
// Kernel A (fused prelude): q-hash + k-dots + k-norm + per-bh max-norm.
// Dot/norm accumulation kept IDENTICAL across rounds (hash sign bits are
// exact-match-critical).
// ---------------------------------------------------------------------------
__global__ __launch_bounds__(256) void prelude_kernel(const float* __restrict__ q,
                                                      const float* __restrict__ k,
                                                      const float* __restrict__ pd,
                                                      float* __restrict__ kdots,
                                                      unsigned int* __restrict__ kmax_bits,
                                                      unsigned char* __restrict__ qh) {
    __shared__ float pds[(DDIM+1)*NPROJ];
    __shared__ float red[256];
    const int tid = threadIdx.x;
    for (int i = tid; i < (DDIM+1)*NPROJ; i += 256) pds[i] = pd[i];
    __syncthreads();

    const int lin = blockIdx.x * 256 + tid;
    const int bh = lin >> 13;

    float acc[NPROJ];
    float4 xv[16];

    {
        const float4* xp = (const float4*)(q + (size_t)lin * DDIM);
        #pragma unroll
        for (int j = 0; j < 16; ++j) xv[j] = xp[j];
        #pragma unroll
        for (int r = 0; r < NPROJ; ++r) acc[r] = 0.f;
        #pragma unroll
        for (int j = 0; j < 16; ++j) {
            float xs[4] = {xv[j].x, xv[j].y, xv[j].z, xv[j].w};
            #pragma unroll
            for (int c = 0; c < 4; ++c) {
                const int d = j*4 + c;
                #pragma unroll
                for (int r = 0; r < NPROJ; ++r) acc[r] += xs[c] * pds[d*NPROJ + r];
            }
        }
        int bin = 0;
        #pragma unroll
        for (int r = 0; r < NPROJ; ++r) bin |= (acc[r] > 0.f) << r;
        qh[lin] = (unsigned char)(bin ^ (bin >> 1));
    }

    float nr;
    {
        const float4* xp = (const float4*)(k + (size_t)lin * DDIM);
        #pragma unroll
        for (int j = 0; j < 16; ++j) xv[j] = xp[j];
        #pragma unroll
        for (int r = 0; r < NPROJ; ++r) acc[r] = 0.f;
        #pragma unroll
        for (int j = 0; j < 16; ++j) {
            float xs[4] = {xv[j].x, xv[j].y, xv[j].z, xv[j].w};
            #pragma unroll
            for (int c = 0; c < 4; ++c) {
                const int d = j*4 + c;
                #pragma unroll
                for (int r = 0; r < NPROJ; ++r) acc[r] += xs[c] * pds[d*NPROJ + r];
            }
        }
        float ss = 0.f;
        #pragma unroll
        for (int j = 0; j < 16; ++j) {
            float4 t = xv[j];
            ss += t.x*t.x + t.y*t.y + t.z*t.z + t.w*t.w;
        }
        nr = sqrtf(ss);
        float4* kd = (float4*)(kdots + (size_t)lin * 8);
        kd[0] = make_float4(acc[0], acc[1], acc[2], acc[3]);
        kd[1] = make_float4(acc[4], acc[5], acc[6], nr);
    }

    red[tid] = nr;
    __syncthreads();
    for (int s = 128; s > 0; s >>= 1) {
        if (tid < s) red[tid] = fmaxf(red[tid], red[tid+s]);
        __syncthreads();
    }
    if (tid == 0) atomicMax(&kmax_bits[bh], __float_as_uint(red[0]));
}

// ---------------------------------------------------------------------------
// Kernel B: k-hash from stored dots + kmax
// ---------------------------------------------------------------------------
__global__ __launch_bounds__(256) void khash_kernel(const float* __restrict__ pd,
                                                    const float* __restrict__ kdots,
                                                    const unsigned int* __restrict__ kmax_bits,
                                                    unsigned char* __restrict__ kh) {
    const int lin = blockIdx.x * 256 + threadIdx.x;
    const int bh = lin >> 13;
    const float4* kd = (const float4*)(kdots + (size_t)lin * 8);
    float4 d0 = kd[0], d1 = kd[1];
    float acc[NPROJ] = {d0.x, d0.y, d0.z, d0.w, d1.x, d1.y, d1.z};
    const float kn = d1.w;
    const float km = __uint_as_float(kmax_bits[bh]);
    const float ex = sqrtf(fmaxf(km*km - kn*kn, 0.f));
    int bin = 0;
    #pragma unroll
    for (int r = 0; r < NPROJ; ++r) {
        acc[r] += ex * pd[DDIM*NPROJ + r];
        bin |= (acc[r] > 0.f) << r;
    }
    kh[lin] = (unsigned char)(bin ^ (bin >> 1));
}

// ---------------------------------------------------------------------------
// Kernel C: parallel stable counting sort (128 buckets), 256 segs x 32 elems.
// ---------------------------------------------------------------------------
__global__ __launch_bounds__(256) void sort_kernel(const unsigned char* __restrict__ qhash,
                                                   const unsigned char* __restrict__ khash,
                                                   int* __restrict__ qidx,
                                                   int* __restrict__ kidx) {
    __shared__ unsigned char hsh[NSEQ];
    __shared__ unsigned short cnt[128][264];
    __shared__ int base[128];
    __shared__ int wtot[2];
    const int bh = blockIdx.x, tid = threadIdx.x;
    const unsigned char* hash = blockIdx.y ? khash : qhash;
    int* idx = blockIdx.y ? kidx : qidx;

    {
        const uint4* src = (const uint4*)(hash + (size_t)bh * NSEQ);
        uint4* hdst = (uint4*)hsh;
        hdst[tid] = src[tid];
        hdst[tid + 256] = src[tid + 256];
        unsigned int* cz = (unsigned int*)&cnt[0][0];
        for (int i = tid; i < 128*264/2; i += 256) cz[i] = 0;
    }
    __syncthreads();
    {
        const unsigned char* s = hsh + tid*32;
        for (int i = 0; i < 32; ++i) cnt[s[i]][tid]++;
    }
    __syncthreads();

    int sc = 0, vv = 0;
    if (tid < 128) {
        unsigned run = 0;
        uint4* rp = (uint4*)cnt[tid];
        for (int wd = 0; wd < 32; ++wd) {
            uint4 x = rp[wd];
            unsigned v0 = x.x & 0xffffu, v1 = x.x >> 16;
            unsigned v2 = x.y & 0xffffu, v3 = x.y >> 16;
            unsigned v4 = x.z & 0xffffu, v5 = x.z >> 16;
            unsigned v6 = x.w & 0xffffu, v7 = x.w >> 16;
            unsigned p0 = run, p1 = p0+v0, p2 = p1+v1, p3 = p2+v2,
                     p4 = p3+v3, p5 = p4+v4, p6 = p5+v5, p7 = p6+v6;
            run = p7 + v7;
            x.x = p0 | (p1<<16); x.y = p2 | (p3<<16);
            x.z = p4 | (p5<<16); x.w = p6 | (p7<<16);
            rp[wd] = x;
        }
        vv = (int)run;
        sc = vv;
        #pragma unroll
        for (int d = 1; d < 64; d <<= 1) {
            int t = __shfl_up(sc, d, 64);
            if ((tid & 63) >= d) sc += t;
        }
        if ((tid & 63) == 63) wtot[tid >> 6] = sc;
    }
    __syncthreads();
    if (tid < 128) base[tid] = (sc - vv) + (tid >= 64 ? wtot[0] : 0);
    __syncthreads();
    {
        int* dst = idx + (size_t)bh * NSEQ;
        const unsigned char* s = hsh + tid*32;
        for (int i = 0; i < 32; ++i) {
            int h = s[i];
            int c = cnt[h][tid];
            cnt[h][tid] = (unsigned short)(c + 1);
            dst[base[h] + c] = tid*32 + i;
        }
    }
}

// ---------------------------------------------------------------------------
// Kernel D: MFMA fused attention.
//   K/V staged as f32 in LDS via async global_load_lds GATHER (per-lane
//   source = sorted row, linear LDS dest, XOR-16B swizzle on both sides).
//   Double-buffered: issue chunk c+1's 8 gloads -> compute chunk c ->
//   barrier drains. Zero staging VGPRs (r7/r10/r11 showed register staging
//   spills at this pressure). bf16 conversion happens at fragment load
//   (bit-identical values to the old staging path).
//   QK^T 16x16x32 (Q hi/lo, A=K); its C layout (q=lane&15,
//   key=(lane>>4)*4+reg) IS the A-operand layout of 16x16x16bf16_1k for P,
//   so PV = mfma(P, V) from registers, V row-major from LDS.
// ---------------------------------------------------------------------------

#define LN32 3.46573590279972f

template<int PHASE>   // 0 = block-diagonal, 1 = residual
__device__ __forceinline__ void compute_chunk(
    int rc, int lane,
    const bf16x8 (&qhf)[4][2], const bf16x8 (&qlf)[4][2],
    f32x4 (&O)[4][4], float (&lacc)[4],
    const float* maskF, const char* KL, const char* VL) {

    const int lr4 = lane >> 4;
    const int lc  = lane & 15;

    #pragma unroll
    for (int mt = 0; mt < 4; ++mt) {
        const int key = mt*16 + lc;
        const int ks = key & 15;
        const char* KR = KL + key*256;
        // K row f32, swizzled 16B granules: dims lr4*8..+8 and +32
        f32x4 a0 = *(const f32x4*)(KR + (((lr4*2    ) ^ ks) << 4));
        f32x4 a1 = *(const f32x4*)(KR + (((lr4*2 + 1) ^ ks) << 4));
        f32x4 b0 = *(const f32x4*)(KR + (((lr4*2 + 8) ^ ks) << 4));
        f32x4 b1 = *(const f32x4*)(KR + (((lr4*2 + 9) ^ ks) << 4));
        union { bf16x8 v8; unsigned int u[4]; } kh0, kh1;
        kh0.u[0] = pk2bf(a0[0], a0[1]); kh0.u[1] = pk2bf(a0[2], a0[3]);
        kh0.u[2] = pk2bf(a1[0], a1[1]); kh0.u[3] = pk2bf(a1[2], a1[3]);
        kh1.u[0] = pk2bf(b0[0], b0[1]); kh1.u[1] = pk2bf(b0[2], b0[3]);
        kh1.u[2] = pk2bf(b1[0], b1[1]); kh1.u[3] = pk2bf(b1[2], b1[3]);

        float4 mk;
        if (PHASE) mk = *(const float4*)(maskF + rc*64 + mt*16 + lr4*4);

        bf16x4 pa[4];
        #pragma unroll
        for (int qt = 0; qt < 4; ++qt) {
            f32x4 c = {0.f, 0.f, 0.f, 0.f};
            c = __builtin_amdgcn_mfma_f32_16x16x32_bf16(kh0.v8, qhf[qt][0], c, 0, 0, 0);
            c = __builtin_amdgcn_mfma_f32_16x16x32_bf16(kh0.v8, qlf[qt][0], c, 0, 0, 0);
            c = __builtin_amdgcn_mfma_f32_16x16x32_bf16(kh1.v8, qhf[qt][1], c, 0, 0, 0);
            c = __builtin_amdgcn_mfma_f32_16x16x32_bf16(kh1.v8, qlf[qt][1], c, 0, 0, 0);
            float e0, e1, e2, e3;
            if (PHASE) {
                e0 = __expf(c[0] + LN32) * mk.x;
                e1 = __expf(c[1] + LN32) * mk.y;
                e2 = __expf(c[2] + LN32) * mk.z;
                e3 = __expf(c[3] + LN32) * mk.w;
            } else {
                e0 = __expf(c[0]); e1 = __expf(c[1]);
                e2 = __expf(c[2]); e3 = __expf(c[3]);
            }
            lacc[qt] += (e0+e1) + (e2+e3);
            union { bf16x4 v4; unsigned int u[2]; } pw;
            pw.u[0] = pk2bf(e0, e1);
            pw.u[1] = pk2bf(e2, e3);
            pa[qt] = pw.v4;
        }

        __builtin_amdgcn_s_setprio(1);
        #pragma unroll
        for (int dt = 0; dt < 4; ++dt) {
            const int d = dt*16 + lc;
            const int gd = d >> 2, sub = (d & 3) << 2;
            float fv[4];
            #pragma unroll
            for (int r = 0; r < 4; ++r) {
                const int rv = mt*16 + lr4*4 + r;
                fv[r] = *(const float*)(VL + rv*256 + (((gd ^ (rv & 15)) << 4) | sub));
            }
            union { bf16x4 v4; unsigned int u[2]; } vb;
            vb.u[0] = pk2bf(fv[0], fv[1]);
            vb.u[1] = pk2bf(fv[2], fv[3]);
            #pragma unroll
            for (int qt = 0; qt < 4; ++qt)
                O[qt][dt] = __builtin_amdgcn_mfma_f32_16x16x16bf16_1k(pa[qt], vb.v4, O[qt][dt], 0, 0, 0);
        }
        __builtin_amdgcn_s_setprio(0);
    }
}

__global__ __launch_bounds__(256, 2) void attn_kernel(const float* __restrict__ q,
                                                      const float* __restrict__ k,
                                                      const float* __restrict__ v,
                                                      const int* __restrict__ samp,
                                                      const int* __restrict__ qidx,
                                                      const int* __restrict__ kidx,
                                                      float* __restrict__ out) {
    __shared__ __align__(16) char KB2[2][16384];
    __shared__ __align__(16) char VB2[2][16384];
    __shared__ int qidxL[256];
    __shared__ int kidxL[256];
    __shared__ int ridxL[256];
    __shared__ __align__(16) float maskF[256];

    const int g = blockIdx.x, bh = blockIdx.y;
    const int tid = threadIdx.x;
    const int lane = tid & 63, w = tid >> 6;
    const int lr4 = lane >> 4, lc = lane & 15;
    const size_t basef = (size_t)bh * NSEQ * DDIM;
    const float* kb = k + basef;
    const float* vb = v + basef;

    qidxL[tid] = qidx[bh*NSEQ + g*KBLK + tid];
    kidxL[tid] = kidx[bh*NSEQ + g*KBLK + tid];
    {
        int sp = samp[bh*NSAMP + tid];
        ridxL[tid] = kidx[bh*NSEQ + sp];
        maskF[tid] = ((sp >> 8) == g) ? 0.f : 1.f;
    }
    __syncthreads();   // rows tables valid for all threads

    // ---- async-stage helper: 8 gload16 per thread per chunk, 0 VGPRs held ----
    // LDS image: [64 rows][256B f32], 16B granule XOR-swizzled by (row&15);
    // source pre-swizzled so LDS[row*256 + c] = K[rows[row]][swz(c,row)].
    #define STAGE(ROWS, BUF)                                                    \
    {                                                                           \
        _Pragma("unroll")                                                       \
        for (int i = 0; i < 4; ++i) {                                           \
            const int B = i*4096 + w*1024 + lane*16;                            \
            const int row = B >> 8;                                             \
            const int gg = (B & 255) >> 4;                                      \
            const int rr = (ROWS)[row];                                         \
            const int sc = ((gg ^ (row & 15)) << 4) >> 2;                       \
            gload16(kb + (size_t)rr*64 + sc, KB2[BUF] + i*4096 + w*1024);       \
            gload16(vb + (size_t)rr*64 + sc, VB2[BUF] + i*4096 + w*1024);       \
        }                                                                       \
    }

    // prologue: stage chunk 0, then load Q while it lands
    STAGE(kidxL, 0)

    // Q fragments (hi/lo), pre-scaled by 0.125 (exact)
    bf16x8 qhf[4][2], qlf[4][2];
    #pragma unroll
    for (int qt = 0; qt < 4; ++qt) {
        const int qrow = qidxL[w*64 + qt*16 + lc];
        const float* qp = q + basef + (size_t)qrow*DDIM;
        #pragma unroll
        for (int ks = 0; ks < 2; ++ks) {
            const float* p = qp + ks*32 + lr4*8;
            float4 a = *(const float4*)p;
            float4 b = *(const float4*)(p + 4);
            float xs[8] = {a.x,a.y,a.z,a.w,b.x,b.y,b.z,b.w};
            union { bf16x8 v8; unsigned int u[4]; } hv, lv;
            #pragma unroll
            for (int j = 0; j < 4; ++j) {
                float s0 = xs[2*j]   * 0.125f;
                float s1 = xs[2*j+1] * 0.125f;
                unsigned hp = pk2bf(s0, s1);
                hv.u[j] = hp;
                float l0 = s0 - __uint_as_float(hp << 16);
                float l1 = s1 - __uint_as_float(hp & 0xffff0000u);
                lv.u[j] = pk2bf(l0, l1);
            }
            qhf[qt][ks] = hv.v8; qlf[qt][ks] = lv.v8;
        }
    }

    f32x4 O[4][4];
    #pragma unroll
    for (int a = 0; a < 4; ++a)
        #pragma unroll
        for (int b = 0; b < 4; ++b) O[a][b] = (f32x4){0.f,0.f,0.f,0.f};
    float lacc[4] = {0,0,0,0};

    __syncthreads();   // chunk 0 landed

    for (int ch = 0; ch < 8; ++ch) {
        if (ch < 7) {
            const int nch = ch + 1;
            if (nch < 4) { STAGE(kidxL + nch*64, (nch & 1)) }
            else         { STAGE(ridxL + (nch-4)*64, (nch & 1)) }
        }
        if (ch < 4) compute_chunk<0>(ch,   lane, qhf, qlf, O, lacc, maskF, KB2[ch&1], VB2[ch&1]);
        else        compute_chunk<1>(ch-4, lane, qhf, qlf, O, lacc, maskF, KB2[ch&1], VB2[ch&1]);
        __syncthreads();   // drains the async loads issued above + buffer reuse
    }
    #undef STAGE

    // ---- epilogue: O layout => q=(lane>>4)*4+reg, d=dt*16+lc ----
    #pragma unroll
    for (int qt = 0; qt < 4; ++qt) {
        lacc[qt] += __shfl_xor(lacc[qt], 16, 64);
        lacc[qt] += __shfl_xor(lacc[qt], 32, 64);
        lacc[qt] = 1.f / lacc[qt];
    }
    float* ob = out + basef;
    #pragma unroll
    for (int qt = 0; qt < 4; ++qt) {
        #pragma unroll
        for (int r = 0; r < 4; ++r) {
            const float f = __shfl(lacc[qt], (lane & 48) | (lr4*4 + r), 64);
            const int orow = qidxL[w*64 + qt*16 + lr4*4 + r];
            float* p = ob + (size_t)orow*DDIM + lc;
            #pragma unroll
            for (int dt = 0; dt < 4; ++dt) p[dt*16] = O[qt][dt][r] * f;
        }
    }
}

// ---------------------------------------------------------------------------
extern "C" void kernel_launch(void* const* d_in, const int* in_sizes, int n_in,
                              void* d_out, int out_size, void* d_ws, size_t ws_size,
                              hipStream_t stream) {
    const float* q    = (const float*)d_in[0];
    const float* k    = (const float*)d_in[1];
    const float* v    = (const float*)d_in[2];
    const float* pd   = (const float*)d_in[3];
    const int*   samp = (const int*)d_in[4];
    float* out = (float*)d_out;

    char* ws = (char*)d_ws;
    int*           qidx  = (int*)(ws + 0);
    int*           kidx  = (int*)(ws + (1<<20));
    float*         kdots = (float*)(ws + (2<<20));            // dead after khash
    unsigned char* qh    = (unsigned char*)(ws + (10<<20));
    unsigned char* kh    = (unsigned char*)(ws + (10<<20) + 262144);
    unsigned int*  kmaxb = (unsigned int*)(ws + (11<<20));

    hipMemsetAsync(kmaxb, 0, NBH*sizeof(unsigned int), stream);
    hipLaunchKernelGGL(prelude_kernel, dim3(NBH*NSEQ/256), dim3(256), 0, stream,
                       q, k, pd, kdots, kmaxb, qh);
    hipLaunchKernelGGL(khash_kernel, dim3(NBH*NSEQ/256), dim3(256), 0, stream,
                       pd, kdots, kmaxb, kh);
    hipLaunchKernelGGL(sort_kernel, dim3(NBH, 2), dim3(256), 0, stream, qh, kh, qidx, kidx);
    hipLaunchKernelGGL(attn_kernel, dim3(NB, NBH), dim3(256), 0, stream,
                       q, k, v, samp, qidx, kidx, out);
}